// Round 5
// baseline (220.028 us; speedup 1.0000x reference)
//
#include <hip/hip_runtime.h>

// ---------------- problem constants ----------------
#define BB   8
#define KQ   64
#define HDIM 2048
#define NH   16
#define NKV  4
#define HD   128
#define CTX  4096
#define TTOT 4160      // CTX + KQ
#define NTILES 65      // TTOT / 64
#define LOG2E 1.4426950408889634f
#define SCALE 0.08838834764831845f  // 1/sqrt(128)
#define QSCALE (SCALE * LOG2E)      // folded into Q; exp2-domain softmax
// |q.k| <= 128 after RMS-norm => |sc| <= 128*QSCALE = 16.33. Fixed softmax max.
#define MFIX 16.34f

typedef unsigned short u16;
typedef unsigned int   u32;
typedef __attribute__((ext_vector_type(8))) short  s16x8;   // bf16 storage
typedef __attribute__((ext_vector_type(4))) unsigned short u16x4;
typedef __attribute__((ext_vector_type(4))) float  f32x4;
typedef __bf16 bf16x8 __attribute__((ext_vector_type(8)));  // MFMA operand

__device__ __forceinline__ u16 f2bf(float f) {              // HW RNE cvt
    union { __bf16 h; u16 u; } v; v.h = (__bf16)f; return v.u;
}
__device__ __forceinline__ float bf2f(u16 u) {
    union { float f; u32 u; } v; v.u = ((u32)u) << 16;
    return v.f;
}
__device__ __forceinline__ u32 pack2(float a, float b) {
    return (u32)f2bf(a) | ((u32)f2bf(b) << 16);
}
__device__ __forceinline__ f32x4 mfma16(bf16x8 a, bf16x8 b, f32x4 c) {
    return __builtin_amdgcn_mfma_f32_16x16x32_bf16(a, b, c, 0, 0, 0);
}
// XOR-swizzled byte offsets (conflict-free b128 LDS; see G4/T2)
__device__ __forceinline__ int offK(int row, int colByte) {   // 256B rows
    return row * 256 + (colByte ^ ((row & 7) << 4));
}
__device__ __forceinline__ int offV(int row, int colByte) {   // 128B rows
    return row * 128 + (colByte ^ ((row & 7) << 4));
}

// ---------------- 64x64-tile GEMM core (f32 in, bf16 MFMA, f32 out) -------
// 256 threads = 4 waves, wave = 32x32 sub-tile, BK=64, XOR-swizzled LDS.
__device__ __forceinline__ void gemm64_body(
    const float* __restrict__ Ab, const float* __restrict__ Bb,
    float* __restrict__ Cb, const int ldc, const int Kd,
    u16* Ash, u16* Bsh)
{
    const int tid = threadIdx.x, lane = tid & 63;
    const int w = tid >> 6, wm = w >> 1, wn = w & 1;
    const int l15 = lane & 15, l4 = lane >> 4;
    const int srow = tid >> 2, scol = (tid & 3) * 16;   // 16 f32 per thread

    f32x4 acc[2][2];
#pragma unroll
    for (int i = 0; i < 2; ++i)
#pragma unroll
        for (int j = 0; j < 2; ++j) acc[i][j] = (f32x4){0.f, 0.f, 0.f, 0.f};

    const float* ap = Ab + (size_t)srow * Kd + scol;
    const float* bp = Bb + (size_t)srow * Kd + scol;
    float4 ra0 = *(const float4*)ap,       ra1 = *(const float4*)(ap + 4);
    float4 ra2 = *(const float4*)(ap + 8), ra3 = *(const float4*)(ap + 12);
    float4 rb0 = *(const float4*)bp,       rb1 = *(const float4*)(bp + 4);
    float4 rb2 = *(const float4*)(bp + 8), rb3 = *(const float4*)(bp + 12);

    const int wb0 = offV(srow, 2 * scol);        // A/B tiles have 128B rows
    const int wb1 = offV(srow, 2 * scol + 16);

    for (int k0 = 0; k0 < Kd; k0 += 64) {
        __syncthreads();
        {
            s16x8 av0, av1, bv0, bv1;
            av0[0]=(short)f2bf(ra0.x); av0[1]=(short)f2bf(ra0.y); av0[2]=(short)f2bf(ra0.z); av0[3]=(short)f2bf(ra0.w);
            av0[4]=(short)f2bf(ra1.x); av0[5]=(short)f2bf(ra1.y); av0[6]=(short)f2bf(ra1.z); av0[7]=(short)f2bf(ra1.w);
            av1[0]=(short)f2bf(ra2.x); av1[1]=(short)f2bf(ra2.y); av1[2]=(short)f2bf(ra2.z); av1[3]=(short)f2bf(ra2.w);
            av1[4]=(short)f2bf(ra3.x); av1[5]=(short)f2bf(ra3.y); av1[6]=(short)f2bf(ra3.z); av1[7]=(short)f2bf(ra3.w);
            bv0[0]=(short)f2bf(rb0.x); bv0[1]=(short)f2bf(rb0.y); bv0[2]=(short)f2bf(rb0.z); bv0[3]=(short)f2bf(rb0.w);
            bv0[4]=(short)f2bf(rb1.x); bv0[5]=(short)f2bf(rb1.y); bv0[6]=(short)f2bf(rb1.z); bv0[7]=(short)f2bf(rb1.w);
            bv1[0]=(short)f2bf(rb2.x); bv1[1]=(short)f2bf(rb2.y); bv1[2]=(short)f2bf(rb2.z); bv1[3]=(short)f2bf(rb2.w);
            bv1[4]=(short)f2bf(rb3.x); bv1[5]=(short)f2bf(rb3.y); bv1[6]=(short)f2bf(rb3.z); bv1[7]=(short)f2bf(rb3.w);
            *(s16x8*)((char*)Ash + wb0) = av0;
            *(s16x8*)((char*)Ash + wb1) = av1;
            *(s16x8*)((char*)Bsh + wb0) = bv0;
            *(s16x8*)((char*)Bsh + wb1) = bv1;
        }
        __syncthreads();
        if (k0 + 64 < Kd) {
            const float* ap2 = ap + k0 + 64;
            const float* bp2 = bp + k0 + 64;
            ra0 = *(const float4*)ap2;       ra1 = *(const float4*)(ap2 + 4);
            ra2 = *(const float4*)(ap2 + 8); ra3 = *(const float4*)(ap2 + 12);
            rb0 = *(const float4*)bp2;       rb1 = *(const float4*)(bp2 + 4);
            rb2 = *(const float4*)(bp2 + 8); rb3 = *(const float4*)(bp2 + 12);
        }
#pragma unroll
        for (int ks = 0; ks < 2; ++ks) {
            bf16x8 am[2], bb[2];
#pragma unroll
            for (int i = 0; i < 2; ++i) {
                am[i] = *(const bf16x8*)((const char*)Ash + offV(wm * 32 + i * 16 + l15, 64 * ks + 16 * l4));
                bb[i] = *(const bf16x8*)((const char*)Bsh + offV(wn * 32 + i * 16 + l15, 64 * ks + 16 * l4));
            }
#pragma unroll
            for (int i = 0; i < 2; ++i)
#pragma unroll
                for (int j = 0; j < 2; ++j)
                    acc[i][j] = mfma16(am[i], bb[j], acc[i][j]);
        }
    }

    float* Cw = Cb + (size_t)(wm * 32) * ldc + wn * 32;
#pragma unroll
    for (int i = 0; i < 2; ++i)
#pragma unroll
        for (int j = 0; j < 2; ++j)
#pragma unroll
            for (int r = 0; r < 4; ++r)
                Cw[(size_t)(i * 16 + l4 * 4 + r) * ldc + j * 16 + l15] = acc[i][j][r];
}

// QKV fused projection: grid (8, 48).  y<32: wq, 32..39: wk, 40..47: wv.
__global__ __launch_bounds__(256) void gemm_qkv(
    const float* __restrict__ hs, const float* __restrict__ wq,
    const float* __restrict__ wk, const float* __restrict__ wv,
    float* __restrict__ qkv)
{
    __shared__ __align__(16) u16 Ash[64 * 64];
    __shared__ __align__(16) u16 Bsh[64 * 64];
    const int by = blockIdx.y;
    const float* Bt;
    if (by < 32)      Bt = wq + (size_t)by * 64 * HDIM;
    else if (by < 40) Bt = wk + (size_t)(by - 32) * 64 * HDIM;
    else              Bt = wv + (size_t)(by - 40) * 64 * HDIM;
    const float* Ab = hs + (size_t)blockIdx.x * 64 * HDIM;
    float* Cb = qkv + (size_t)blockIdx.x * 64 * 3072 + by * 64;
    gemm64_body(Ab, Bt, Cb, 3072, HDIM, Ash, Bsh);
}

// generic: C[M,N] = A[M,Kd] * Bt[N,Kd]^T, grid (M/64, N/64)
__global__ __launch_bounds__(256) void gemm64(
    const float* __restrict__ A, const float* __restrict__ Bt,
    float* __restrict__ C, const int ldc, const int Kd)
{
    __shared__ __align__(16) u16 Ash[64 * 64];
    __shared__ __align__(16) u16 Bsh[64 * 64];
    const float* Ab = A + (size_t)blockIdx.x * 64 * Kd;
    const float* Bb = Bt + (size_t)blockIdx.y * 64 * Kd;
    float* Cb = C + (size_t)blockIdx.x * 64 * ldc + blockIdx.y * 64;
    gemm64_body(Ab, Bb, Cb, ldc, Kd, Ash, Bsh);
}

// ---------------- shared RMSNorm+RoPE helper (half-wave, float2-paired) ---
// lane j in [0,32): handles d = {2j,2j+1} and {2j+64,2j+65}; writes 2x u32.
__device__ __forceinline__ void norm_rope_row(
    const float* __restrict__ src, const float* __restrict__ wgt,
    const float* __restrict__ cosT, const float* __restrict__ sinT,
    int pos, int j, float outScale, u16* __restrict__ dst)
{
    float2 xa = *(const float2*)(src + 2 * j);
    float2 xb = *(const float2*)(src + 2 * j + 64);
    float ss = xa.x * xa.x + xa.y * xa.y + xb.x * xb.x + xb.y * xb.y;
#pragma unroll
    for (int m = 1; m < 32; m <<= 1) ss += __shfl_xor(ss, m);
    const float rr = rsqrtf(ss * (1.0f / 128.0f) + 1e-6f);
    float2 wa = *(const float2*)(wgt + 2 * j);
    float2 wb = *(const float2*)(wgt + 2 * j + 64);
    const float* cp = cosT + (size_t)pos * 128;
    const float* sp = sinT + (size_t)pos * 128;
    float2 ca = *(const float2*)(cp + 2 * j), cb = *(const float2*)(cp + 2 * j + 64);
    float2 sa = *(const float2*)(sp + 2 * j), sb = *(const float2*)(sp + 2 * j + 64);
    const float nax = xa.x * rr * wa.x, nay = xa.y * rr * wa.y;
    const float nbx = xb.x * rr * wb.x, nby = xb.y * rr * wb.y;
    const float lox = (nax * ca.x - nbx * sa.x) * outScale;
    const float loy = (nay * ca.y - nby * sa.y) * outScale;
    const float hix = (nbx * cb.x + nax * sb.x) * outScale;
    const float hiy = (nby * cb.y + nay * sb.y) * outScale;
    ((u32*)dst)[j]      = pack2(lox, loy);
    ((u32*)dst)[j + 32] = pack2(hix, hiy);
}

// ---------------- Q finalize: half-wave per (bq,h); grid 1024x256 ---------
__global__ __launch_bounds__(256) void finalize_q(
    const float* __restrict__ qkv, const float* __restrict__ qw,
    const float* __restrict__ cosT, const float* __restrict__ sinT, u16* __restrict__ Qb)
{
    const int unit = blockIdx.x * 8 + (threadIdx.x >> 5);   // bq*16 + h
    const int j = threadIdx.x & 31;
    const int bq = unit >> 4, h = unit & 15;
    const int b = bq >> 6, q = bq & 63;
    norm_rope_row(qkv + (size_t)bq * 3072 + h * 128, qw, cosT, sinT,
                  CTX + q, j, QSCALE,
                  Qb + ((size_t)((b * 16 + h) * 64 + q)) * 128);
}

// ---------------- ctx K build: half-wave per (b,pos,kv); grid 16384x256 ---
__global__ __launch_bounds__(256) void build_k(
    const float* __restrict__ ctxk, const float* __restrict__ kw,
    const float* __restrict__ cosT, const float* __restrict__ sinT, u16* __restrict__ Kb)
{
    const int unit = blockIdx.x * 8 + (threadIdx.x >> 5);   // (b*4096+pos)*4 + kv
    const int j = threadIdx.x & 31;
    const int kv = unit & 3, rid = unit >> 2;
    const int b = rid >> 12, pos = rid & 4095;
    norm_rope_row(ctxk + ((size_t)rid * 4 + kv) * 128, kw, cosT, sinT,
                  pos, j, 1.0f,
                  Kb + ((size_t)(b * 4 + kv) * TTOT + pos) * 128);
}

// ---------------- ctx V^T build: VtG[(b,kv), d, pos] ----------------------
__global__ __launch_bounds__(256) void build_vt(
    const float* __restrict__ ctxv, u16* __restrict__ VtG)
{
    const int pt = blockIdx.x, kv = blockIdx.y, b = blockIdx.z;
    const int t = threadIdx.x;
    const int d = t & 127, half = t >> 7;
    const int p0 = pt * 64 + half * 32;

    u16* dst = VtG + ((size_t)(b * 4 + kv) * 128 + d) * TTOT + p0;
    const float* src = ctxv + ((size_t)(b * 4096 + p0) * 4 + kv) * 128 + d;
#pragma unroll
    for (int j8 = 0; j8 < 4; ++j8) {
        s16x8 v;
#pragma unroll
        for (int je = 0; je < 8; ++je)
            v[je] = (short)f2bf(src[(size_t)(j8 * 8 + je) * 512]);
        *(s16x8*)(dst + j8 * 8) = v;
    }
}

// ---------------- noise K + V^T build (positions CTX..CTX+63) -------------
// half-wave per (bq, kv); grid 256x256.
__global__ __launch_bounds__(256) void build_noise(
    const float* __restrict__ qkv, const float* __restrict__ kw,
    const float* __restrict__ cosT, const float* __restrict__ sinT,
    u16* __restrict__ Kb, u16* __restrict__ VtG)
{
    const int unit = blockIdx.x * 8 + (threadIdx.x >> 5);   // bq*4 + kv
    const int j = threadIdx.x & 31;
    const int kv = unit & 3, bq = unit >> 2;
    const int b = bq >> 6, q = bq & 63;
    const int pos = CTX + q;

    norm_rope_row(qkv + (size_t)bq * 3072 + 2048 + kv * 128, kw, cosT, sinT,
                  pos, j, 1.0f,
                  Kb + ((size_t)(b * 4 + kv) * TTOT + pos) * 128);

    const float* vsrc = qkv + (size_t)bq * 3072 + 2560 + kv * 128;
    float2 va = *(const float2*)(vsrc + 2 * j);
    float2 vb = *(const float2*)(vsrc + 2 * j + 64);
    u16* vt = VtG + (size_t)(b * 4 + kv) * 128 * TTOT;
    vt[(size_t)(2 * j) * TTOT + pos]      = f2bf(va.x);
    vt[(size_t)(2 * j + 1) * TTOT + pos]  = f2bf(va.y);
    vt[(size_t)(2 * j + 64) * TTOT + pos] = f2bf(vb.x);
    vt[(size_t)(2 * j + 65) * TTOT + pos] = f2bf(vb.y);
}

// ---------------- flash attention partial (split-KV, fixed-max softmax) ---
// grid dim3(S, NKV, B); 512 threads = 8 waves = 4 heads x 2 q-halves.
// XOR-swizzled LDS tiles; coalesced register-layout Opart epilogue.
template <int S>
__global__ __launch_bounds__(512, 2) void attn_partial(
    const u16* __restrict__ Qb, const u16* __restrict__ Kb, const u16* __restrict__ VtG,
    const float* __restrict__ mask, u16* __restrict__ Opart, float* __restrict__ lsum)
{
    __shared__ __align__(16) u16 Ksh[64 * 128];     // [pos][d], XOR swizzle
    __shared__ __align__(16) u16 Vsh[128 * 64];     // [d][pos], XOR swizzle
    __shared__ __align__(16) u16 Psh[8][32 * 40];   // per-wave P chunk

    const int s = blockIdx.x, kv = blockIdx.y, b = blockIdx.z;
    const int tid = threadIdx.x, lane = tid & 63, w = tid >> 6;
    const int h = kv * 4 + (w >> 1);
    const int qh = w & 1, qbase = qh * 32;
    const int l15 = lane & 15, l4 = lane >> 4;
    const int t0 = (NTILES * s) / S, t1 = (NTILES * (s + 1)) / S;

    bf16x8 aq[2][4];
    {
        const u16* qb = Qb + ((size_t)((b * 16 + h) * 64 + qbase)) * 128;
#pragma unroll
        for (int mt = 0; mt < 2; ++mt)
#pragma unroll
            for (int ks = 0; ks < 4; ++ks)
                aq[mt][ks] = *(const bf16x8*)(qb + (mt * 16 + l15) * 128 + ks * 32 + l4 * 8);
    }

    bf16x8 bones;   // col-0 ones -> P row sums via MFMA
    {
        __bf16 e = (l15 == 0) ? (__bf16)1.0f : (__bf16)0.0f;
#pragma unroll
        for (int i = 0; i < 8; ++i) bones[i] = e;
    }

    f32x4 o[2][8], ol[2];
#pragma unroll
    for (int mt = 0; mt < 2; ++mt) {
        ol[mt] = (f32x4){0.f, 0.f, 0.f, 0.f};
#pragma unroll
        for (int nt = 0; nt < 8; ++nt) o[mt][nt] = (f32x4){0.f, 0.f, 0.f, 0.f};
    }

    const u16* Kbase = Kb + (size_t)(b * 4 + kv) * TTOT * 128;
    const u16* Vbase = VtG + (size_t)(b * 4 + kv) * 128 * TTOT;
    const float* mrow = mask + (size_t)b * 64 * TTOT;
    u16* P = Psh[w];

    // staging geometry
    const int kp = tid >> 4, kcb = (tid & 15) * 16;  // K rows kp, kp+32; col byte
    const int vr = tid >> 3, vcb = (tid & 7) * 16;   // V rows vr, vr+64; col byte

    // prologue: stage tile t0
    s16x8 kv0 = *(const s16x8*)(Kbase + (size_t)(t0 * 64 + kp) * 128 + (kcb >> 1));
    s16x8 kv1 = *(const s16x8*)(Kbase + (size_t)(t0 * 64 + kp + 32) * 128 + (kcb >> 1));
    s16x8 vv0 = *(const s16x8*)(Vbase + (size_t)vr * TTOT + t0 * 64 + (vcb >> 1));
    s16x8 vv1 = *(const s16x8*)(Vbase + (size_t)(vr + 64) * TTOT + t0 * 64 + (vcb >> 1));
    *(s16x8*)((char*)Ksh + offK(kp, kcb)) = kv0;
    *(s16x8*)((char*)Ksh + offK(kp + 32, kcb)) = kv1;
    *(s16x8*)((char*)Vsh + offV(vr, vcb)) = vv0;
    *(s16x8*)((char*)Vsh + offV(vr + 64, vcb)) = vv1;
    __syncthreads();

    for (int t = t0; t < t1; ++t) {
        const int p0 = t * 64;
        const bool pf = (t + 1 < t1);
        if (pf) {
            const int p1 = p0 + 64;
            kv0 = *(const s16x8*)(Kbase + (size_t)(p1 + kp) * 128 + (kcb >> 1));
            kv1 = *(const s16x8*)(Kbase + (size_t)(p1 + kp + 32) * 128 + (kcb >> 1));
            vv0 = *(const s16x8*)(Vbase + (size_t)vr * TTOT + p1 + (vcb >> 1));
            vv1 = *(const s16x8*)(Vbase + (size_t)(vr + 64) * TTOT + p1 + (vcb >> 1));
        }

        // S = Q K^T
        f32x4 sc[2][4];
#pragma unroll
        for (int mt = 0; mt < 2; ++mt)
#pragma unroll
            for (int nt = 0; nt < 4; ++nt) sc[mt][nt] = (f32x4){0.f, 0.f, 0.f, 0.f};
#pragma unroll
        for (int nt = 0; nt < 4; ++nt) {
#pragma unroll
            for (int ks = 0; ks < 4; ++ks) {
                bf16x8 bk = *(const bf16x8*)((const char*)Ksh + offK(nt * 16 + l15, 64 * ks + 16 * l4));
                sc[0][nt] = mfma16(aq[0][ks], bk, sc[0][nt]);
                sc[1][nt] = mfma16(aq[1][ks], bk, sc[1][nt]);
            }
        }

        // fixed-max softmax: p = exp2(sc + mask*LOG2E - MFIX)
#pragma unroll
        for (int mt = 0; mt < 2; ++mt) {
#pragma unroll
            for (int r = 0; r < 4; ++r) {
                const int q = qbase + mt * 16 + l4 * 4 + r;
                const float* mq = mrow + (size_t)q * TTOT + p0 + l15;
                sc[mt][0][r] = exp2f(sc[mt][0][r] + fmaf(mq[0],  LOG2E, -MFIX));
                sc[mt][1][r] = exp2f(sc[mt][1][r] + fmaf(mq[16], LOG2E, -MFIX));
                sc[mt][2][r] = exp2f(sc[mt][2][r] + fmaf(mq[32], LOG2E, -MFIX));
                sc[mt][3][r] = exp2f(sc[mt][3][r] + fmaf(mq[48], LOG2E, -MFIX));
            }
        }

        // O += P V ; l += P 1
#pragma unroll
        for (int ks = 0; ks < 2; ++ks) {
#pragma unroll
            for (int mt = 0; mt < 2; ++mt)
#pragma unroll
                for (int r = 0; r < 4; ++r) {
                    P[(mt * 16 + l4 * 4 + r) * 40 + l15]      = f2bf(sc[mt][ks * 2 + 0][r]);
                    P[(mt * 16 + l4 * 4 + r) * 40 + 16 + l15] = f2bf(sc[mt][ks * 2 + 1][r]);
                }
            bf16x8 ap0 = *(const bf16x8*)(P + (l15) * 40 + l4 * 8);
            bf16x8 ap1 = *(const bf16x8*)(P + (16 + l15) * 40 + l4 * 8);
#pragma unroll
            for (int nt = 0; nt < 8; ++nt) {
                bf16x8 bv = *(const bf16x8*)((const char*)Vsh + offV(nt * 16 + l15, 64 * ks + 16 * l4));
                o[0][nt] = mfma16(ap0, bv, o[0][nt]);
                o[1][nt] = mfma16(ap1, bv, o[1][nt]);
            }
            ol[0] = mfma16(ap0, bones, ol[0]);
            ol[1] = mfma16(ap1, bones, ol[1]);
        }

        if (pf) {
            __syncthreads();
            *(s16x8*)((char*)Ksh + offK(kp, kcb)) = kv0;
            *(s16x8*)((char*)Ksh + offK(kp + 32, kcb)) = kv1;
            *(s16x8*)((char*)Vsh + offV(vr, vcb)) = vv0;
            *(s16x8*)((char*)Vsh + offV(vr + 64, vcb)) = vv1;
            __syncthreads();
        }
    }

    // coalesced epilogue: Opart chunk per (b,h,s) = [qh][mt][nt][lane][r] u16
    {
        u16* ob = Opart + ((size_t)((b * 16 + h) * S + s)) * 8192;
#pragma unroll
        for (int mt = 0; mt < 2; ++mt)
#pragma unroll
            for (int nt = 0; nt < 8; ++nt) {
                u16x4 v;
#pragma unroll
                for (int r = 0; r < 4; ++r) v[r] = f2bf(o[mt][nt][r]);
                *(u16x4*)(ob + (((qh * 2 + mt) * 8 + nt) * 64 + lane) * 4) = v;
            }
        if (l15 == 0) {
#pragma unroll
            for (int mt = 0; mt < 2; ++mt)
#pragma unroll
                for (int r = 0; r < 4; ++r) {
                    const int q = qbase + mt * 16 + l4 * 4 + r;
                    lsum[((size_t)((b * 16 + h) * 64 + q)) * S + s] = ol[mt][r];
                }
        }
    }
}

// ---------------- merge splits -> attn (B,K,NH*HD) f32 --------------------
// one wave per (b,h,qh); grid 64x256. Reads Opart register layout with b64.
template <int S>
__global__ __launch_bounds__(256) void merge_kernel(
    const u16* __restrict__ Opart, const float* __restrict__ lsum, float* __restrict__ attnb)
{
    const int wid = blockIdx.x * 4 + (threadIdx.x >> 6);   // (b*16+h)*2 + qh
    const int lane = threadIdx.x & 63;
    const int l15 = lane & 15, l4 = lane >> 4;
    const int qh = wid & 1, bh = wid >> 1;
    const int h = bh & 15, b = bh >> 4;

    // per-lane (lane<32 meaningful) L for q = qh*32 + (lane&31)
    float L = 0.f;
    {
        const float* lr = lsum + ((size_t)bh * 64 + qh * 32 + (lane & 31)) * S;
#pragma unroll
        for (int s2 = 0; s2 < S; ++s2) L += lr[s2];
    }
    const float invL = 1.0f / L;

    float acc[2][8][4];
#pragma unroll
    for (int mt = 0; mt < 2; ++mt)
#pragma unroll
        for (int nt = 0; nt < 8; ++nt)
#pragma unroll
            for (int r = 0; r < 4; ++r) acc[mt][nt][r] = 0.f;

    for (int s2 = 0; s2 < S; ++s2) {
        const u16* ob = Opart + ((size_t)(bh * S + s2)) * 8192;
#pragma unroll
        for (int mt = 0; mt < 2; ++mt)
#pragma unroll
            for (int nt = 0; nt < 8; ++nt) {
                u16x4 v = *(const u16x4*)(ob + (((qh * 2 + mt) * 8 + nt) * 64 + lane) * 4);
#pragma unroll
                for (int r = 0; r < 4; ++r) acc[mt][nt][r] += bf2f(v[r]);
            }
    }

#pragma unroll
    for (int mt = 0; mt < 2; ++mt)
#pragma unroll
        for (int r = 0; r < 4; ++r) {
            const float wl = __shfl(invL, mt * 16 + l4 * 4 + r);
            const int q = qh * 32 + mt * 16 + l4 * 4 + r;
            float* dst = attnb + (size_t)(b * 64 + q) * 2048 + h * 128;
#pragma unroll
            for (int nt = 0; nt < 8; ++nt)
                dst[nt * 16 + l15] = acc[mt][nt][r] * wl;
        }
}

// ---------------- launch ----------------
extern "C" void kernel_launch(void* const* d_in, const int* in_sizes, int n_in,
                              void* d_out, int out_size, void* d_ws, size_t ws_size,
                              hipStream_t stream)
{
    (void)in_sizes; (void)n_in; (void)out_size;
    const float* hs   = (const float*)d_in[0];
    const float* ctxk = (const float*)d_in[1];
    const float* ctxv = (const float*)d_in[2];
    const float* mask = (const float*)d_in[3];
    const float* cosT = (const float*)d_in[4];
    const float* sinT = (const float*)d_in[5];
    const float* wq   = (const float*)d_in[6];
    const float* wk   = (const float*)d_in[7];
    const float* wv   = (const float*)d_in[8];
    const float* wo   = (const float*)d_in[9];
    const float* qnw  = (const float*)d_in[10];
    const float* knw  = (const float*)d_in[11];

    auto align256 = [](size_t b) { return (b + 255) & ~(size_t)255; };
    auto need = [&](int S) {
        return align256((size_t)512 * 3072 * 4)                 // qkv
             + align256((size_t)BB * NH * 64 * 128 * 2)         // Qb
             + align256((size_t)BB * NKV * TTOT * 128 * 2)      // Kb
             + align256((size_t)BB * NKV * TTOT * 128 * 2)      // VtG
             + align256((size_t)BB * NH * S * 8192 * 2)         // Opart
             + align256((size_t)BB * NH * 64 * S * 4)           // lsum
             + align256((size_t)512 * 2048 * 4);                // attnb
    };
    const int S = (ws_size >= need(16)) ? 16 : 8;

    char* ws = (char*)d_ws;
    size_t off = 0;
    auto carve = [&](size_t bytes) -> void* {
        void* p = ws + off;
        off += (bytes + 255) & ~(size_t)255;
        return p;
    };
    float* qkv   = (float*)carve((size_t)512 * 3072 * 4);
    u16*   Qb    = (u16*)carve((size_t)BB * NH * 64 * 128 * 2);
    u16*   Kb    = (u16*)carve((size_t)BB * NKV * TTOT * 128 * 2);
    u16*   VtG   = (u16*)carve((size_t)BB * NKV * TTOT * 128 * 2);
    u16*   Opart = (u16*)carve((size_t)BB * NH * S * 8192 * 2);
    float* lsumb = (float*)carve((size_t)BB * NH * 64 * S * 4);
    float* attnb = (float*)carve((size_t)512 * 2048 * 4);

    gemm_qkv<<<dim3(8, 48), 256, 0, stream>>>(hs, wq, wk, wv, qkv);
    finalize_q <<<1024,  256, 0, stream>>>(qkv, qnw, cosT, sinT, Qb);
    build_k    <<<16384, 256, 0, stream>>>(ctxk, knw, cosT, sinT, Kb);
    build_vt   <<<dim3(64, NKV, BB), 256, 0, stream>>>(ctxv, VtG);
    build_noise<<<256,   256, 0, stream>>>(qkv, knw, cosT, sinT, Kb, VtG);
    if (S == 16) {
        attn_partial<16><<<dim3(16, NKV, BB), 512, 0, stream>>>(Qb, Kb, VtG, mask, Opart, lsumb);
        merge_kernel<16><<<64, 256, 0, stream>>>(Opart, lsumb, attnb);
    } else {
        attn_partial<8><<<dim3(8, NKV, BB), 512, 0, stream>>>(Qb, Kb, VtG, mask, Opart, lsumb);
        merge_kernel<8><<<64, 256, 0, stream>>>(Opart, lsumb, attnb);
    }
    gemm64<<<dim3(8, 32), 256, 0, stream>>>(attnb, wo, (float*)d_out, 2048, 2048);
}

// Round 6
// 186.196 us; speedup vs baseline: 1.1817x; 1.1817x over previous
//
#include <hip/hip_runtime.h>

// ---------------- problem constants ----------------
#define BB   8
#define KQ   64
#define HDIM 2048
#define NH   16
#define NKV  4
#define HD   128
#define CTX  4096
#define TTOT 4160      // CTX + KQ
#define NTILES 65      // TTOT / 64
#define LOG2E 1.4426950408889634f
#define SCALE 0.08838834764831845f  // 1/sqrt(128)
#define QSCALE (SCALE * LOG2E)      // folded into Q; exp2-domain softmax
// |q.k| <= 128 after RMS-norm => |sc| <= 128*QSCALE = 16.33. Fixed softmax max.
#define MFIX 16.34f

typedef unsigned short u16;
typedef unsigned int   u32;
typedef __attribute__((ext_vector_type(8))) short  s16x8;   // bf16 storage
typedef __attribute__((ext_vector_type(4))) unsigned short u16x4;
typedef __attribute__((ext_vector_type(4))) float  f32x4;
typedef __bf16 bf16x8 __attribute__((ext_vector_type(8)));  // MFMA operand

__device__ __forceinline__ u16 f2bf(float f) {              // HW RNE cvt
    union { __bf16 h; u16 u; } v; v.h = (__bf16)f; return v.u;
}
__device__ __forceinline__ float bf2f(u16 u) {
    union { float f; u32 u; } v; v.u = ((u32)u) << 16;
    return v.f;
}
__device__ __forceinline__ u32 pack2(float a, float b) {
    return (u32)f2bf(a) | ((u32)f2bf(b) << 16);
}
__device__ __forceinline__ f32x4 mfma16(bf16x8 a, bf16x8 b, f32x4 c) {
    return __builtin_amdgcn_mfma_f32_16x16x32_bf16(a, b, c, 0, 0, 0);
}

// ---------------- 64x64-tile GEMM core (round-4 proven: padded LDS) -------
__device__ __forceinline__ void gemm64_body(
    const float* __restrict__ Ab, const float* __restrict__ Bb,
    float* __restrict__ Cb, const int ldc, const int Kd,
    u16* Ash, u16* Bsh)
{
    const int tid = threadIdx.x, lane = tid & 63;
    const int w = tid >> 6, wm = w >> 1, wn = w & 1;
    const int l15 = lane & 15, l4 = lane >> 4;
    const int srow = tid >> 2, scol = (tid & 3) * 16;

    f32x4 acc[2][2];
#pragma unroll
    for (int i = 0; i < 2; ++i)
#pragma unroll
        for (int j = 0; j < 2; ++j) acc[i][j] = (f32x4){0.f, 0.f, 0.f, 0.f};

    const float* ap = Ab + (size_t)srow * Kd + scol;
    const float* bp = Bb + (size_t)srow * Kd + scol;
    float4 ra0 = *(const float4*)ap,       ra1 = *(const float4*)(ap + 4);
    float4 ra2 = *(const float4*)(ap + 8), ra3 = *(const float4*)(ap + 12);
    float4 rb0 = *(const float4*)bp,       rb1 = *(const float4*)(bp + 4);
    float4 rb2 = *(const float4*)(bp + 8), rb3 = *(const float4*)(bp + 12);

    for (int k0 = 0; k0 < Kd; k0 += 64) {
        __syncthreads();
        {
            s16x8 av0, av1, bv0, bv1;
            av0[0]=(short)f2bf(ra0.x); av0[1]=(short)f2bf(ra0.y); av0[2]=(short)f2bf(ra0.z); av0[3]=(short)f2bf(ra0.w);
            av0[4]=(short)f2bf(ra1.x); av0[5]=(short)f2bf(ra1.y); av0[6]=(short)f2bf(ra1.z); av0[7]=(short)f2bf(ra1.w);
            av1[0]=(short)f2bf(ra2.x); av1[1]=(short)f2bf(ra2.y); av1[2]=(short)f2bf(ra2.z); av1[3]=(short)f2bf(ra2.w);
            av1[4]=(short)f2bf(ra3.x); av1[5]=(short)f2bf(ra3.y); av1[6]=(short)f2bf(ra3.z); av1[7]=(short)f2bf(ra3.w);
            bv0[0]=(short)f2bf(rb0.x); bv0[1]=(short)f2bf(rb0.y); bv0[2]=(short)f2bf(rb0.z); bv0[3]=(short)f2bf(rb0.w);
            bv0[4]=(short)f2bf(rb1.x); bv0[5]=(short)f2bf(rb1.y); bv0[6]=(short)f2bf(rb1.z); bv0[7]=(short)f2bf(rb1.w);
            bv1[0]=(short)f2bf(rb2.x); bv1[1]=(short)f2bf(rb2.y); bv1[2]=(short)f2bf(rb2.z); bv1[3]=(short)f2bf(rb2.w);
            bv1[4]=(short)f2bf(rb3.x); bv1[5]=(short)f2bf(rb3.y); bv1[6]=(short)f2bf(rb3.z); bv1[7]=(short)f2bf(rb3.w);
            *(s16x8*)(Ash + srow * 72 + scol)     = av0;
            *(s16x8*)(Ash + srow * 72 + scol + 8) = av1;
            *(s16x8*)(Bsh + srow * 72 + scol)     = bv0;
            *(s16x8*)(Bsh + srow * 72 + scol + 8) = bv1;
        }
        __syncthreads();
        if (k0 + 64 < Kd) {
            const float* ap2 = ap + k0 + 64;
            const float* bp2 = bp + k0 + 64;
            ra0 = *(const float4*)ap2;       ra1 = *(const float4*)(ap2 + 4);
            ra2 = *(const float4*)(ap2 + 8); ra3 = *(const float4*)(ap2 + 12);
            rb0 = *(const float4*)bp2;       rb1 = *(const float4*)(bp2 + 4);
            rb2 = *(const float4*)(bp2 + 8); rb3 = *(const float4*)(bp2 + 12);
        }
#pragma unroll
        for (int ks = 0; ks < 2; ++ks) {
            bf16x8 am[2], bb[2];
#pragma unroll
            for (int i = 0; i < 2; ++i) {
                am[i] = *(const bf16x8*)(Ash + (wm * 32 + i * 16 + l15) * 72 + ks * 32 + l4 * 8);
                bb[i] = *(const bf16x8*)(Bsh + (wn * 32 + i * 16 + l15) * 72 + ks * 32 + l4 * 8);
            }
#pragma unroll
            for (int i = 0; i < 2; ++i)
#pragma unroll
                for (int j = 0; j < 2; ++j)
                    acc[i][j] = mfma16(am[i], bb[j], acc[i][j]);
        }
    }

    float* Cw = Cb + (size_t)(wm * 32) * ldc + wn * 32;
#pragma unroll
    for (int i = 0; i < 2; ++i)
#pragma unroll
        for (int j = 0; j < 2; ++j)
#pragma unroll
            for (int r = 0; r < 4; ++r)
                Cw[(size_t)(i * 16 + l4 * 4 + r) * ldc + j * 16 + l15] = acc[i][j][r];
}

__global__ __launch_bounds__(256) void gemm_qkv(
    const float* __restrict__ hs, const float* __restrict__ wq,
    const float* __restrict__ wk, const float* __restrict__ wv,
    float* __restrict__ qkv)
{
    __shared__ __align__(16) u16 Ash[64 * 72];
    __shared__ __align__(16) u16 Bsh[64 * 72];
    const int by = blockIdx.y;
    const float* Bt;
    if (by < 32)      Bt = wq + (size_t)by * 64 * HDIM;
    else if (by < 40) Bt = wk + (size_t)(by - 32) * 64 * HDIM;
    else              Bt = wv + (size_t)(by - 40) * 64 * HDIM;
    const float* Ab = hs + (size_t)blockIdx.x * 64 * HDIM;
    float* Cb = qkv + (size_t)blockIdx.x * 64 * 3072 + by * 64;
    gemm64_body(Ab, Bt, Cb, 3072, HDIM, Ash, Bsh);
}

__global__ __launch_bounds__(256) void gemm64(
    const float* __restrict__ A, const float* __restrict__ Bt,
    float* __restrict__ C, const int ldc, const int Kd)
{
    __shared__ __align__(16) u16 Ash[64 * 72];
    __shared__ __align__(16) u16 Bsh[64 * 72];
    const float* Ab = A + (size_t)blockIdx.x * 64 * Kd;
    const float* Bb = Bt + (size_t)blockIdx.y * 64 * Kd;
    float* Cb = C + (size_t)blockIdx.x * 64 * ldc + blockIdx.y * 64;
    gemm64_body(Ab, Bb, Cb, ldc, Kd, Ash, Bsh);
}

// ---------------- shared RMSNorm+RoPE helper (half-wave, float2-paired) ---
__device__ __forceinline__ void norm_rope_row(
    const float* __restrict__ src, const float* __restrict__ wgt,
    const float* __restrict__ cosT, const float* __restrict__ sinT,
    int pos, int j, float outScale, u16* __restrict__ dst)
{
    float2 xa = *(const float2*)(src + 2 * j);
    float2 xb = *(const float2*)(src + 2 * j + 64);
    float ss = xa.x * xa.x + xa.y * xa.y + xb.x * xb.x + xb.y * xb.y;
#pragma unroll
    for (int m = 1; m < 32; m <<= 1) ss += __shfl_xor(ss, m);
    const float rr = rsqrtf(ss * (1.0f / 128.0f) + 1e-6f);
    float2 wa = *(const float2*)(wgt + 2 * j);
    float2 wb = *(const float2*)(wgt + 2 * j + 64);
    const float* cp = cosT + (size_t)pos * 128;
    const float* sp = sinT + (size_t)pos * 128;
    float2 ca = *(const float2*)(cp + 2 * j), cb = *(const float2*)(cp + 2 * j + 64);
    float2 sa = *(const float2*)(sp + 2 * j), sb = *(const float2*)(sp + 2 * j + 64);
    const float nax = xa.x * rr * wa.x, nay = xa.y * rr * wa.y;
    const float nbx = xb.x * rr * wb.x, nby = xb.y * rr * wb.y;
    const float lox = (nax * ca.x - nbx * sa.x) * outScale;
    const float loy = (nay * ca.y - nby * sa.y) * outScale;
    const float hix = (nbx * cb.x + nax * sb.x) * outScale;
    const float hiy = (nby * cb.y + nay * sb.y) * outScale;
    ((u32*)dst)[j]      = pack2(lox, loy);
    ((u32*)dst)[j + 32] = pack2(hix, hiy);
}

__global__ __launch_bounds__(256) void finalize_q(
    const float* __restrict__ qkv, const float* __restrict__ qw,
    const float* __restrict__ cosT, const float* __restrict__ sinT, u16* __restrict__ Qb)
{
    const int unit = blockIdx.x * 8 + (threadIdx.x >> 5);   // bq*16 + h
    const int j = threadIdx.x & 31;
    const int bq = unit >> 4, h = unit & 15;
    const int b = bq >> 6, q = bq & 63;
    norm_rope_row(qkv + (size_t)bq * 3072 + h * 128, qw, cosT, sinT,
                  CTX + q, j, QSCALE,
                  Qb + ((size_t)((b * 16 + h) * 64 + q)) * 128);
}

__global__ __launch_bounds__(256) void build_k(
    const float* __restrict__ ctxk, const float* __restrict__ kw,
    const float* __restrict__ cosT, const float* __restrict__ sinT, u16* __restrict__ Kb)
{
    const int unit = blockIdx.x * 8 + (threadIdx.x >> 5);   // (b*4096+pos)*4 + kv
    const int j = threadIdx.x & 31;
    const int kv = unit & 3, rid = unit >> 2;
    const int b = rid >> 12, pos = rid & 4095;
    norm_rope_row(ctxk + ((size_t)rid * 4 + kv) * 128, kw, cosT, sinT,
                  pos, j, 1.0f,
                  Kb + ((size_t)(b * 4 + kv) * TTOT + pos) * 128);
}

__global__ __launch_bounds__(256) void build_vt(
    const float* __restrict__ ctxv, u16* __restrict__ VtG)
{
    const int pt = blockIdx.x, kv = blockIdx.y, b = blockIdx.z;
    const int t = threadIdx.x;
    const int d = t & 127, half = t >> 7;
    const int p0 = pt * 64 + half * 32;

    u16* dst = VtG + ((size_t)(b * 4 + kv) * 128 + d) * TTOT + p0;
    const float* src = ctxv + ((size_t)(b * 4096 + p0) * 4 + kv) * 128 + d;
#pragma unroll
    for (int j8 = 0; j8 < 4; ++j8) {
        s16x8 v;
#pragma unroll
        for (int je = 0; je < 8; ++je)
            v[je] = (short)f2bf(src[(size_t)(j8 * 8 + je) * 512]);
        *(s16x8*)(dst + j8 * 8) = v;
    }
}

__global__ __launch_bounds__(256) void build_noise(
    const float* __restrict__ qkv, const float* __restrict__ kw,
    const float* __restrict__ cosT, const float* __restrict__ sinT,
    u16* __restrict__ Kb, u16* __restrict__ VtG)
{
    const int unit = blockIdx.x * 8 + (threadIdx.x >> 5);   // bq*4 + kv
    const int j = threadIdx.x & 31;
    const int kv = unit & 3, bq = unit >> 2;
    const int b = bq >> 6, q = bq & 63;
    const int pos = CTX + q;

    norm_rope_row(qkv + (size_t)bq * 3072 + 2048 + kv * 128, kw, cosT, sinT,
                  pos, j, 1.0f,
                  Kb + ((size_t)(b * 4 + kv) * TTOT + pos) * 128);

    const float* vsrc = qkv + (size_t)bq * 3072 + 2560 + kv * 128;
    float2 va = *(const float2*)(vsrc + 2 * j);
    float2 vb = *(const float2*)(vsrc + 2 * j + 64);
    u16* vt = VtG + (size_t)(b * 4 + kv) * 128 * TTOT;
    vt[(size_t)(2 * j) * TTOT + pos]      = f2bf(va.x);
    vt[(size_t)(2 * j + 1) * TTOT + pos]  = f2bf(va.y);
    vt[(size_t)(2 * j + 64) * TTOT + pos] = f2bf(vb.x);
    vt[(size_t)(2 * j + 65) * TTOT + pos] = f2bf(vb.y);
}

// ---------------- flash attention partial: pipelined double-buffer --------
// grid dim3(S=8, NKV, B) = 256 blocks = 1 block/CU (LDS 124 KB).
// 512 threads = 8 waves = 4 heads x 2 q-halves, 2 waves/SIMD, VGPR budget 256
// -> prefetch registers stay live (round-4's 128-cap made the compiler sink
// the prefetch loads; that was the ~900cy/tile stall).
// Pipeline per tile: compute(cur) | ds_write(cur^1) <- regs(t+1) | sync |
// issue loads(t+2). Nothing in flight at the barrier => no vmcnt-drain cost.
template <int S>
__global__ __launch_bounds__(512, 2) void attn_partial(
    const u16* __restrict__ Qb, const u16* __restrict__ Kb, const u16* __restrict__ VtG,
    const float* __restrict__ mask, u16* __restrict__ Opart, float* __restrict__ lsum)
{
    __shared__ __align__(16) u16   Ksh[2][64 * 136];   // K [pos][d], padded
    __shared__ __align__(16) u16   Vsh[2][128 * 72];   // V^T [d][pos], padded
    __shared__ __align__(16) float Msh[2][64 * 68];    // mask*log2e - MFIX
    __shared__ __align__(16) u16   Psh[8][32 * 40];    // per-wave P chunk

    const int s = blockIdx.x, kv = blockIdx.y, b = blockIdx.z;
    const int tid = threadIdx.x, lane = tid & 63, w = tid >> 6;
    const int h = kv * 4 + (w >> 1);
    const int qh = w & 1, qbase = qh * 32;
    const int l15 = lane & 15, l4 = lane >> 4;
    const int t0 = (NTILES * s) / S, t1 = (NTILES * (s + 1)) / S;

    bf16x8 aq[2][4];
    {
        const u16* qb = Qb + ((size_t)((b * 16 + h) * 64 + qbase)) * 128;
#pragma unroll
        for (int mt = 0; mt < 2; ++mt)
#pragma unroll
            for (int ks = 0; ks < 4; ++ks)
                aq[mt][ks] = *(const bf16x8*)(qb + (mt * 16 + l15) * 128 + ks * 32 + l4 * 8);
    }

    bf16x8 bones;   // col-0 ones -> P row sums via MFMA
    {
        __bf16 e = (l15 == 0) ? (__bf16)1.0f : (__bf16)0.0f;
#pragma unroll
        for (int i = 0; i < 8; ++i) bones[i] = e;
    }

    f32x4 o[2][8], ol[2];
#pragma unroll
    for (int mt = 0; mt < 2; ++mt) {
        ol[mt] = (f32x4){0.f, 0.f, 0.f, 0.f};
#pragma unroll
        for (int nt = 0; nt < 8; ++nt) o[mt][nt] = (f32x4){0.f, 0.f, 0.f, 0.f};
    }

    const u16* Kbase = Kb + (size_t)(b * 4 + kv) * TTOT * 128;
    const u16* Vbase = VtG + (size_t)(b * 4 + kv) * 128 * TTOT;
    const float* mrow = mask + (size_t)b * 64 * TTOT;
    u16* P = Psh[w];

    // staging geometry
    const int kp = tid >> 4, kd8 = (tid & 15) * 8;   // K rows kp, kp+32
    const int vr = tid >> 3, vc8 = (tid & 7) * 8;    // V rows vr, vr+64
    const int mq_ = tid >> 3, mk8 = (tid & 7) * 8;   // mask row, col block

    s16x8 rk0, rk1, rv0, rv1;
    float4 rm0, rm1;

    auto ld = [&](int t) {
        const int p = t * 64;
        rk0 = *(const s16x8*)(Kbase + (size_t)(p + kp) * 128 + kd8);
        rk1 = *(const s16x8*)(Kbase + (size_t)(p + kp + 32) * 128 + kd8);
        rv0 = *(const s16x8*)(Vbase + (size_t)vr * TTOT + p + vc8);
        rv1 = *(const s16x8*)(Vbase + (size_t)(vr + 64) * TTOT + p + vc8);
        const float* mp = mrow + (size_t)mq_ * TTOT + p + mk8;
        rm0 = *(const float4*)mp;
        rm1 = *(const float4*)(mp + 4);
        __builtin_amdgcn_sched_barrier(0);   // pin load issue here
    };
    auto st = [&](int buf) {
        *(s16x8*)(Ksh[buf] + kp * 136 + kd8) = rk0;
        *(s16x8*)(Ksh[buf] + (kp + 32) * 136 + kd8) = rk1;
        *(s16x8*)(Vsh[buf] + vr * 72 + vc8) = rv0;
        *(s16x8*)(Vsh[buf] + (vr + 64) * 72 + vc8) = rv1;
        float* md = Msh[buf] + mq_ * 68 + mk8;
        md[0] = fmaf(rm0.x, LOG2E, -MFIX); md[1] = fmaf(rm0.y, LOG2E, -MFIX);
        md[2] = fmaf(rm0.z, LOG2E, -MFIX); md[3] = fmaf(rm0.w, LOG2E, -MFIX);
        md[4] = fmaf(rm1.x, LOG2E, -MFIX); md[5] = fmaf(rm1.y, LOG2E, -MFIX);
        md[6] = fmaf(rm1.z, LOG2E, -MFIX); md[7] = fmaf(rm1.w, LOG2E, -MFIX);
    };

    // prologue
    ld(t0);
    st(0);
    __syncthreads();
    if (t0 + 1 < t1) ld(t0 + 1);

    int cur = 0;
    for (int t = t0; t < t1; ++t) {
        // ---- compute tile t from buf[cur] ----
        f32x4 sc[2][4];
#pragma unroll
        for (int mt = 0; mt < 2; ++mt)
#pragma unroll
            for (int nt = 0; nt < 4; ++nt) sc[mt][nt] = (f32x4){0.f, 0.f, 0.f, 0.f};
#pragma unroll
        for (int nt = 0; nt < 4; ++nt) {
#pragma unroll
            for (int ks = 0; ks < 4; ++ks) {
                bf16x8 bk = *(const bf16x8*)(Ksh[cur] + (nt * 16 + l15) * 136 + ks * 32 + l4 * 8);
                sc[0][nt] = mfma16(aq[0][ks], bk, sc[0][nt]);
                sc[1][nt] = mfma16(aq[1][ks], bk, sc[1][nt]);
            }
        }

        // fixed-max softmax: p = exp2(sc + msh), msh = mask*log2e - MFIX
#pragma unroll
        for (int mt = 0; mt < 2; ++mt) {
#pragma unroll
            for (int r = 0; r < 4; ++r) {
                const int q = qbase + mt * 16 + l4 * 4 + r;
                const float* mq = Msh[cur] + q * 68 + l15;
                sc[mt][0][r] = exp2f(sc[mt][0][r] + mq[0]);
                sc[mt][1][r] = exp2f(sc[mt][1][r] + mq[16]);
                sc[mt][2][r] = exp2f(sc[mt][2][r] + mq[32]);
                sc[mt][3][r] = exp2f(sc[mt][3][r] + mq[48]);
            }
        }

        // O += P V ; l += P 1
#pragma unroll
        for (int ks = 0; ks < 2; ++ks) {
#pragma unroll
            for (int mt = 0; mt < 2; ++mt)
#pragma unroll
                for (int r = 0; r < 4; ++r) {
                    P[(mt * 16 + l4 * 4 + r) * 40 + l15]      = f2bf(sc[mt][ks * 2 + 0][r]);
                    P[(mt * 16 + l4 * 4 + r) * 40 + 16 + l15] = f2bf(sc[mt][ks * 2 + 1][r]);
                }
            bf16x8 ap0 = *(const bf16x8*)(P + (l15) * 40 + l4 * 8);
            bf16x8 ap1 = *(const bf16x8*)(P + (16 + l15) * 40 + l4 * 8);
#pragma unroll
            for (int nt = 0; nt < 8; ++nt) {
                bf16x8 bv = *(const bf16x8*)(Vsh[cur] + (nt * 16 + l15) * 72 + ks * 32 + l4 * 8);
                o[0][nt] = mfma16(ap0, bv, o[0][nt]);
                o[1][nt] = mfma16(ap1, bv, o[1][nt]);
            }
            ol[0] = mfma16(ap0, bones, ol[0]);
            ol[1] = mfma16(ap1, bones, ol[1]);
        }

        // ---- stage tile t+1 into buf[cur^1]; prefetch t+2 ----
        if (t + 1 < t1) st(cur ^ 1);      // waits vmcnt for ld(t+1) regs here
        __syncthreads();                  // vmcnt already 0: no drain cost
        if (t + 2 < t1) ld(t + 2);        // in flight across next compute
        cur ^= 1;
    }

    // coalesced epilogue: Opart chunk per (b,h,s) = [qh][mt][nt][lane][r] u16
    {
        u16* ob = Opart + ((size_t)((b * 16 + h) * S + s)) * 8192;
#pragma unroll
        for (int mt = 0; mt < 2; ++mt)
#pragma unroll
            for (int nt = 0; nt < 8; ++nt) {
                u16x4 v;
#pragma unroll
                for (int r = 0; r < 4; ++r) v[r] = f2bf(o[mt][nt][r]);
                *(u16x4*)(ob + (((qh * 2 + mt) * 8 + nt) * 64 + lane) * 4) = v;
            }
        if (l15 == 0) {
#pragma unroll
            for (int mt = 0; mt < 2; ++mt)
#pragma unroll
                for (int r = 0; r < 4; ++r) {
                    const int q = qbase + mt * 16 + l4 * 4 + r;
                    lsum[((size_t)((b * 16 + h) * 64 + q)) * S + s] = ol[mt][r];
                }
        }
    }
}

// ---------------- merge splits -> attn (B,K,NH*HD) f32 --------------------
template <int S>
__global__ __launch_bounds__(256) void merge_kernel(
    const u16* __restrict__ Opart, const float* __restrict__ lsum, float* __restrict__ attnb)
{
    const int wid = blockIdx.x * 4 + (threadIdx.x >> 6);   // (b*16+h)*2 + qh
    const int lane = threadIdx.x & 63;
    const int l15 = lane & 15, l4 = lane >> 4;
    const int qh = wid & 1, bh = wid >> 1;
    const int h = bh & 15, b = bh >> 4;

    float L = 0.f;
    {
        const float* lr = lsum + ((size_t)bh * 64 + qh * 32 + (lane & 31)) * S;
#pragma unroll
        for (int s2 = 0; s2 < S; ++s2) L += lr[s2];
    }
    const float invL = 1.0f / L;

    float acc[2][8][4];
#pragma unroll
    for (int mt = 0; mt < 2; ++mt)
#pragma unroll
        for (int nt = 0; nt < 8; ++nt)
#pragma unroll
            for (int r = 0; r < 4; ++r) acc[mt][nt][r] = 0.f;

    for (int s2 = 0; s2 < S; ++s2) {
        const u16* ob = Opart + ((size_t)(bh * S + s2)) * 8192;
#pragma unroll
        for (int mt = 0; mt < 2; ++mt)
#pragma unroll
            for (int nt = 0; nt < 8; ++nt) {
                u16x4 v = *(const u16x4*)(ob + (((qh * 2 + mt) * 8 + nt) * 64 + lane) * 4);
#pragma unroll
                for (int r = 0; r < 4; ++r) acc[mt][nt][r] += bf2f(v[r]);
            }
    }

#pragma unroll
    for (int mt = 0; mt < 2; ++mt)
#pragma unroll
        for (int r = 0; r < 4; ++r) {
            const float wl = __shfl(invL, mt * 16 + l4 * 4 + r);
            const int q = qh * 32 + mt * 16 + l4 * 4 + r;
            float* dst = attnb + (size_t)(b * 64 + q) * 2048 + h * 128;
#pragma unroll
            for (int nt = 0; nt < 8; ++nt)
                dst[nt * 16 + l15] = acc[mt][nt][r] * wl;
        }
}

// ---------------- launch ----------------
extern "C" void kernel_launch(void* const* d_in, const int* in_sizes, int n_in,
                              void* d_out, int out_size, void* d_ws, size_t ws_size,
                              hipStream_t stream)
{
    (void)in_sizes; (void)n_in; (void)out_size; (void)ws_size;
    const float* hs   = (const float*)d_in[0];
    const float* ctxk = (const float*)d_in[1];
    const float* ctxv = (const float*)d_in[2];
    const float* mask = (const float*)d_in[3];
    const float* cosT = (const float*)d_in[4];
    const float* sinT = (const float*)d_in[5];
    const float* wq   = (const float*)d_in[6];
    const float* wk   = (const float*)d_in[7];
    const float* wv   = (const float*)d_in[8];
    const float* wo   = (const float*)d_in[9];
    const float* qnw  = (const float*)d_in[10];
    const float* knw  = (const float*)d_in[11];

    const int S = 8;   // grid 256 = 1 block/CU; pipelined dbuf attn

    char* ws = (char*)d_ws;
    size_t off = 0;
    auto carve = [&](size_t bytes) -> void* {
        void* p = ws + off;
        off += (bytes + 255) & ~(size_t)255;
        return p;
    };
    float* qkv   = (float*)carve((size_t)512 * 3072 * 4);
    u16*   Qb    = (u16*)carve((size_t)BB * NH * 64 * 128 * 2);
    u16*   Kb    = (u16*)carve((size_t)BB * NKV * TTOT * 128 * 2);
    u16*   VtG   = (u16*)carve((size_t)BB * NKV * TTOT * 128 * 2);
    u16*   Opart = (u16*)carve((size_t)BB * NH * S * 8192 * 2);
    float* lsumb = (float*)carve((size_t)BB * NH * 64 * S * 4);
    float* attnb = (float*)carve((size_t)512 * 2048 * 4);

    gemm_qkv<<<dim3(8, 48), 256, 0, stream>>>(hs, wq, wk, wv, qkv);
    finalize_q <<<1024,  256, 0, stream>>>(qkv, qnw, cosT, sinT, Qb);
    build_k    <<<16384, 256, 0, stream>>>(ctxk, knw, cosT, sinT, Kb);
    build_vt   <<<dim3(64, NKV, BB), 256, 0, stream>>>(ctxv, VtG);
    build_noise<<<256,   256, 0, stream>>>(qkv, knw, cosT, sinT, Kb, VtG);
    attn_partial<8><<<dim3(8, NKV, BB), 512, 0, stream>>>(Qb, Kb, VtG, mask, Opart, lsumb);
    merge_kernel<8><<<64, 256, 0, stream>>>(Opart, lsumb, attnb);
    gemm64<<<dim3(8, 32), 256, 0, stream>>>(attnb, wo, (float*)d_out, 2048, 2048);
}

// Round 7
// 178.695 us; speedup vs baseline: 1.2313x; 1.0420x over previous
//
#include <hip/hip_runtime.h>

// ---------------- problem constants ----------------
#define BB   8
#define KQ   64
#define HDIM 2048
#define NH   16
#define NKV  4
#define HD   128
#define CTX  4096
#define TTOT 4160      // CTX + KQ
#define NTILES 65      // TTOT / 64
#define LOG2E 1.4426950408889634f
#define SCALE 0.08838834764831845f  // 1/sqrt(128)
#define QSCALE (SCALE * LOG2E)      // folded into Q; exp2-domain softmax
// |q.k| <= 128 after RMS-norm => |sc| <= 128*QSCALE = 16.33. Fixed softmax max.
#define MFIX 16.34f

typedef unsigned short u16;
typedef unsigned int   u32;
typedef __attribute__((ext_vector_type(8))) short  s16x8;   // bf16 storage
typedef __attribute__((ext_vector_type(4))) unsigned short u16x4;
typedef __attribute__((ext_vector_type(4))) float  f32x4;
typedef __bf16 bf16x8 __attribute__((ext_vector_type(8)));  // MFMA operand

__device__ __forceinline__ u16 f2bf(float f) {              // HW RNE cvt
    union { __bf16 h; u16 u; } v; v.h = (__bf16)f; return v.u;
}
__device__ __forceinline__ float bf2f(u16 u) {
    union { float f; u32 u; } v; v.u = ((u32)u) << 16;
    return v.f;
}
__device__ __forceinline__ u32 pack2(float a, float b) {
    return (u32)f2bf(a) | ((u32)f2bf(b) << 16);
}
__device__ __forceinline__ f32x4 mfma16(bf16x8 a, bf16x8 b, f32x4 c) {
    return __builtin_amdgcn_mfma_f32_16x16x32_bf16(a, b, c, 0, 0, 0);
}

// ---------------- 64x64-tile GEMM core (padded LDS, live prefetch) --------
// 256 threads = 4 waves, wave = 32x32 sub-tile, BK=64.
// MUST be compiled with a low min-occupancy bound: at the default the
// compiler picks ~48 VGPR (8 waves/SIMD it never gets: grid ~1.5 blk/CU)
// and sinks the prefetch float4s to their ds_write use -> every K-step
// stalls a full HBM/L2 round-trip at the barrier (round-6: 49us, Mfma 4.5%).
__device__ __forceinline__ void gemm64_body(
    const float* __restrict__ Ab, const float* __restrict__ Bb,
    float* __restrict__ Cb, const int ldc, const int Kd,
    u16* Ash, u16* Bsh)
{
    const int tid = threadIdx.x, lane = tid & 63;
    const int w = tid >> 6, wm = w >> 1, wn = w & 1;
    const int l15 = lane & 15, l4 = lane >> 4;
    const int srow = tid >> 2, scol = (tid & 3) * 16;

    f32x4 acc[2][2];
#pragma unroll
    for (int i = 0; i < 2; ++i)
#pragma unroll
        for (int j = 0; j < 2; ++j) acc[i][j] = (f32x4){0.f, 0.f, 0.f, 0.f};

    const float* ap = Ab + (size_t)srow * Kd + scol;
    const float* bp = Bb + (size_t)srow * Kd + scol;
    float4 ra0 = *(const float4*)ap,       ra1 = *(const float4*)(ap + 4);
    float4 ra2 = *(const float4*)(ap + 8), ra3 = *(const float4*)(ap + 12);
    float4 rb0 = *(const float4*)bp,       rb1 = *(const float4*)(bp + 4);
    float4 rb2 = *(const float4*)(bp + 8), rb3 = *(const float4*)(bp + 12);
    __builtin_amdgcn_sched_barrier(0);

    for (int k0 = 0; k0 < Kd; k0 += 64) {
        __syncthreads();
        {
            s16x8 av0, av1, bv0, bv1;
            av0[0]=(short)f2bf(ra0.x); av0[1]=(short)f2bf(ra0.y); av0[2]=(short)f2bf(ra0.z); av0[3]=(short)f2bf(ra0.w);
            av0[4]=(short)f2bf(ra1.x); av0[5]=(short)f2bf(ra1.y); av0[6]=(short)f2bf(ra1.z); av0[7]=(short)f2bf(ra1.w);
            av1[0]=(short)f2bf(ra2.x); av1[1]=(short)f2bf(ra2.y); av1[2]=(short)f2bf(ra2.z); av1[3]=(short)f2bf(ra2.w);
            av1[4]=(short)f2bf(ra3.x); av1[5]=(short)f2bf(ra3.y); av1[6]=(short)f2bf(ra3.z); av1[7]=(short)f2bf(ra3.w);
            bv0[0]=(short)f2bf(rb0.x); bv0[1]=(short)f2bf(rb0.y); bv0[2]=(short)f2bf(rb0.z); bv0[3]=(short)f2bf(rb0.w);
            bv0[4]=(short)f2bf(rb1.x); bv0[5]=(short)f2bf(rb1.y); bv0[6]=(short)f2bf(rb1.z); bv0[7]=(short)f2bf(rb1.w);
            bv1[0]=(short)f2bf(rb2.x); bv1[1]=(short)f2bf(rb2.y); bv1[2]=(short)f2bf(rb2.z); bv1[3]=(short)f2bf(rb2.w);
            bv1[4]=(short)f2bf(rb3.x); bv1[5]=(short)f2bf(rb3.y); bv1[6]=(short)f2bf(rb3.z); bv1[7]=(short)f2bf(rb3.w);
            *(s16x8*)(Ash + srow * 72 + scol)     = av0;
            *(s16x8*)(Ash + srow * 72 + scol + 8) = av1;
            *(s16x8*)(Bsh + srow * 72 + scol)     = bv0;
            *(s16x8*)(Bsh + srow * 72 + scol + 8) = bv1;
        }
        __syncthreads();
        if (k0 + 64 < Kd) {   // issue next loads; live across MFMA phase
            const float* ap2 = ap + k0 + 64;
            const float* bp2 = bp + k0 + 64;
            ra0 = *(const float4*)ap2;       ra1 = *(const float4*)(ap2 + 4);
            ra2 = *(const float4*)(ap2 + 8); ra3 = *(const float4*)(ap2 + 12);
            rb0 = *(const float4*)bp2;       rb1 = *(const float4*)(bp2 + 4);
            rb2 = *(const float4*)(bp2 + 8); rb3 = *(const float4*)(bp2 + 12);
            __builtin_amdgcn_sched_barrier(0);   // pin load issue here
        }
#pragma unroll
        for (int ks = 0; ks < 2; ++ks) {
            bf16x8 am[2], bb[2];
#pragma unroll
            for (int i = 0; i < 2; ++i) {
                am[i] = *(const bf16x8*)(Ash + (wm * 32 + i * 16 + l15) * 72 + ks * 32 + l4 * 8);
                bb[i] = *(const bf16x8*)(Bsh + (wn * 32 + i * 16 + l15) * 72 + ks * 32 + l4 * 8);
            }
#pragma unroll
            for (int i = 0; i < 2; ++i)
#pragma unroll
                for (int j = 0; j < 2; ++j)
                    acc[i][j] = mfma16(am[i], bb[j], acc[i][j]);
        }
    }

    float* Cw = Cb + (size_t)(wm * 32) * ldc + wn * 32;
#pragma unroll
    for (int i = 0; i < 2; ++i)
#pragma unroll
        for (int j = 0; j < 2; ++j)
#pragma unroll
            for (int r = 0; r < 4; ++r)
                Cw[(size_t)(i * 16 + l4 * 4 + r) * ldc + j * 16 + l15] = acc[i][j][r];
}

// min-waves 2 (=> 2 blocks/CU, VGPR cap ~256): prefetch regs stay live.
__global__ __launch_bounds__(256, 2) void gemm_qkv(
    const float* __restrict__ hs, const float* __restrict__ wq,
    const float* __restrict__ wk, const float* __restrict__ wv,
    float* __restrict__ qkv)
{
    __shared__ __align__(16) u16 Ash[64 * 72];
    __shared__ __align__(16) u16 Bsh[64 * 72];
    const int by = blockIdx.y;
    const float* Bt;
    if (by < 32)      Bt = wq + (size_t)by * 64 * HDIM;
    else if (by < 40) Bt = wk + (size_t)(by - 32) * 64 * HDIM;
    else              Bt = wv + (size_t)(by - 40) * 64 * HDIM;
    const float* Ab = hs + (size_t)blockIdx.x * 64 * HDIM;
    float* Cb = qkv + (size_t)blockIdx.x * 64 * 3072 + by * 64;
    gemm64_body(Ab, Bt, Cb, 3072, HDIM, Ash, Bsh);
}

__global__ __launch_bounds__(256, 2) void gemm64(
    const float* __restrict__ A, const float* __restrict__ Bt,
    float* __restrict__ C, const int ldc, const int Kd)
{
    __shared__ __align__(16) u16 Ash[64 * 72];
    __shared__ __align__(16) u16 Bsh[64 * 72];
    const float* Ab = A + (size_t)blockIdx.x * 64 * Kd;
    const float* Bb = Bt + (size_t)blockIdx.y * 64 * Kd;
    float* Cb = C + (size_t)blockIdx.x * 64 * ldc + blockIdx.y * 64;
    gemm64_body(Ab, Bb, Cb, ldc, Kd, Ash, Bsh);
}

// ---------------- shared RMSNorm+RoPE helper (half-wave, float2-paired) ---
__device__ __forceinline__ void norm_rope_row(
    const float* __restrict__ src, const float* __restrict__ wgt,
    const float* __restrict__ cosT, const float* __restrict__ sinT,
    int pos, int j, float outScale, u16* __restrict__ dst)
{
    float2 xa = *(const float2*)(src + 2 * j);
    float2 xb = *(const float2*)(src + 2 * j + 64);
    float ss = xa.x * xa.x + xa.y * xa.y + xb.x * xb.x + xb.y * xb.y;
#pragma unroll
    for (int m = 1; m < 32; m <<= 1) ss += __shfl_xor(ss, m);
    const float rr = rsqrtf(ss * (1.0f / 128.0f) + 1e-6f);
    float2 wa = *(const float2*)(wgt + 2 * j);
    float2 wb = *(const float2*)(wgt + 2 * j + 64);
    const float* cp = cosT + (size_t)pos * 128;
    const float* sp = sinT + (size_t)pos * 128;
    float2 ca = *(const float2*)(cp + 2 * j), cb = *(const float2*)(cp + 2 * j + 64);
    float2 sa = *(const float2*)(sp + 2 * j), sb = *(const float2*)(sp + 2 * j + 64);
    const float nax = xa.x * rr * wa.x, nay = xa.y * rr * wa.y;
    const float nbx = xb.x * rr * wb.x, nby = xb.y * rr * wb.y;
    const float lox = (nax * ca.x - nbx * sa.x) * outScale;
    const float loy = (nay * ca.y - nby * sa.y) * outScale;
    const float hix = (nbx * cb.x + nax * sb.x) * outScale;
    const float hiy = (nby * cb.y + nay * sb.y) * outScale;
    ((u32*)dst)[j]      = pack2(lox, loy);
    ((u32*)dst)[j + 32] = pack2(hix, hiy);
}

__global__ __launch_bounds__(256) void finalize_q(
    const float* __restrict__ qkv, const float* __restrict__ qw,
    const float* __restrict__ cosT, const float* __restrict__ sinT, u16* __restrict__ Qb)
{
    const int unit = blockIdx.x * 8 + (threadIdx.x >> 5);   // bq*16 + h
    const int j = threadIdx.x & 31;
    const int bq = unit >> 4, h = unit & 15;
    const int b = bq >> 6, q = bq & 63;
    norm_rope_row(qkv + (size_t)bq * 3072 + h * 128, qw, cosT, sinT,
                  CTX + q, j, QSCALE,
                  Qb + ((size_t)((b * 16 + h) * 64 + q)) * 128);
}

__global__ __launch_bounds__(256) void build_k(
    const float* __restrict__ ctxk, const float* __restrict__ kw,
    const float* __restrict__ cosT, const float* __restrict__ sinT, u16* __restrict__ Kb)
{
    const int unit = blockIdx.x * 8 + (threadIdx.x >> 5);   // (b*4096+pos)*4 + kv
    const int j = threadIdx.x & 31;
    const int kv = unit & 3, rid = unit >> 2;
    const int b = rid >> 12, pos = rid & 4095;
    norm_rope_row(ctxk + ((size_t)rid * 4 + kv) * 128, kw, cosT, sinT,
                  pos, j, 1.0f,
                  Kb + ((size_t)(b * 4 + kv) * TTOT + pos) * 128);
}

__global__ __launch_bounds__(256) void build_vt(
    const float* __restrict__ ctxv, u16* __restrict__ VtG)
{
    const int pt = blockIdx.x, kv = blockIdx.y, b = blockIdx.z;
    const int t = threadIdx.x;
    const int d = t & 127, half = t >> 7;
    const int p0 = pt * 64 + half * 32;

    u16* dst = VtG + ((size_t)(b * 4 + kv) * 128 + d) * TTOT + p0;
    const float* src = ctxv + ((size_t)(b * 4096 + p0) * 4 + kv) * 128 + d;
#pragma unroll
    for (int j8 = 0; j8 < 4; ++j8) {
        s16x8 v;
#pragma unroll
        for (int je = 0; je < 8; ++je)
            v[je] = (short)f2bf(src[(size_t)(j8 * 8 + je) * 512]);
        *(s16x8*)(dst + j8 * 8) = v;
    }
}

__global__ __launch_bounds__(256) void build_noise(
    const float* __restrict__ qkv, const float* __restrict__ kw,
    const float* __restrict__ cosT, const float* __restrict__ sinT,
    u16* __restrict__ Kb, u16* __restrict__ VtG)
{
    const int unit = blockIdx.x * 8 + (threadIdx.x >> 5);   // bq*4 + kv
    const int j = threadIdx.x & 31;
    const int kv = unit & 3, bq = unit >> 2;
    const int b = bq >> 6, q = bq & 63;
    const int pos = CTX + q;

    norm_rope_row(qkv + (size_t)bq * 3072 + 2048 + kv * 128, kw, cosT, sinT,
                  pos, j, 1.0f,
                  Kb + ((size_t)(b * 4 + kv) * TTOT + pos) * 128);

    const float* vsrc = qkv + (size_t)bq * 3072 + 2560 + kv * 128;
    float2 va = *(const float2*)(vsrc + 2 * j);
    float2 vb = *(const float2*)(vsrc + 2 * j + 64);
    u16* vt = VtG + (size_t)(b * 4 + kv) * 128 * TTOT;
    vt[(size_t)(2 * j) * TTOT + pos]      = f2bf(va.x);
    vt[(size_t)(2 * j + 1) * TTOT + pos]  = f2bf(va.y);
    vt[(size_t)(2 * j + 64) * TTOT + pos] = f2bf(vb.x);
    vt[(size_t)(2 * j + 65) * TTOT + pos] = f2bf(vb.y);
}

// ---------------- flash attention partial: pipelined double-buffer --------
// (round-6 proven: 1 block/CU, LDS 124 KB, loads never in flight at barrier)
template <int S>
__global__ __launch_bounds__(512, 2) void attn_partial(
    const u16* __restrict__ Qb, const u16* __restrict__ Kb, const u16* __restrict__ VtG,
    const float* __restrict__ mask, u16* __restrict__ Opart, float* __restrict__ lsum)
{
    __shared__ __align__(16) u16   Ksh[2][64 * 136];   // K [pos][d], padded
    __shared__ __align__(16) u16   Vsh[2][128 * 72];   // V^T [d][pos], padded
    __shared__ __align__(16) float Msh[2][64 * 68];    // mask*log2e - MFIX
    __shared__ __align__(16) u16   Psh[8][32 * 40];    // per-wave P chunk

    const int s = blockIdx.x, kv = blockIdx.y, b = blockIdx.z;
    const int tid = threadIdx.x, lane = tid & 63, w = tid >> 6;
    const int h = kv * 4 + (w >> 1);
    const int qh = w & 1, qbase = qh * 32;
    const int l15 = lane & 15, l4 = lane >> 4;
    const int t0 = (NTILES * s) / S, t1 = (NTILES * (s + 1)) / S;

    bf16x8 aq[2][4];
    {
        const u16* qb = Qb + ((size_t)((b * 16 + h) * 64 + qbase)) * 128;
#pragma unroll
        for (int mt = 0; mt < 2; ++mt)
#pragma unroll
            for (int ks = 0; ks < 4; ++ks)
                aq[mt][ks] = *(const bf16x8*)(qb + (mt * 16 + l15) * 128 + ks * 32 + l4 * 8);
    }

    bf16x8 bones;   // col-0 ones -> P row sums via MFMA
    {
        __bf16 e = (l15 == 0) ? (__bf16)1.0f : (__bf16)0.0f;
#pragma unroll
        for (int i = 0; i < 8; ++i) bones[i] = e;
    }

    f32x4 o[2][8], ol[2];
#pragma unroll
    for (int mt = 0; mt < 2; ++mt) {
        ol[mt] = (f32x4){0.f, 0.f, 0.f, 0.f};
#pragma unroll
        for (int nt = 0; nt < 8; ++nt) o[mt][nt] = (f32x4){0.f, 0.f, 0.f, 0.f};
    }

    const u16* Kbase = Kb + (size_t)(b * 4 + kv) * TTOT * 128;
    const u16* Vbase = VtG + (size_t)(b * 4 + kv) * 128 * TTOT;
    const float* mrow = mask + (size_t)b * 64 * TTOT;
    u16* P = Psh[w];

    const int kp = tid >> 4, kd8 = (tid & 15) * 8;   // K rows kp, kp+32
    const int vr = tid >> 3, vc8 = (tid & 7) * 8;    // V rows vr, vr+64
    const int mq_ = tid >> 3, mk8 = (tid & 7) * 8;   // mask row, col block

    s16x8 rk0, rk1, rv0, rv1;
    float4 rm0, rm1;

    auto ld = [&](int t) {
        const int p = t * 64;
        rk0 = *(const s16x8*)(Kbase + (size_t)(p + kp) * 128 + kd8);
        rk1 = *(const s16x8*)(Kbase + (size_t)(p + kp + 32) * 128 + kd8);
        rv0 = *(const s16x8*)(Vbase + (size_t)vr * TTOT + p + vc8);
        rv1 = *(const s16x8*)(Vbase + (size_t)(vr + 64) * TTOT + p + vc8);
        const float* mp = mrow + (size_t)mq_ * TTOT + p + mk8;
        rm0 = *(const float4*)mp;
        rm1 = *(const float4*)(mp + 4);
        __builtin_amdgcn_sched_barrier(0);   // pin load issue here
    };
    auto st = [&](int buf) {
        *(s16x8*)(Ksh[buf] + kp * 136 + kd8) = rk0;
        *(s16x8*)(Ksh[buf] + (kp + 32) * 136 + kd8) = rk1;
        *(s16x8*)(Vsh[buf] + vr * 72 + vc8) = rv0;
        *(s16x8*)(Vsh[buf] + (vr + 64) * 72 + vc8) = rv1;
        float* md = Msh[buf] + mq_ * 68 + mk8;
        md[0] = fmaf(rm0.x, LOG2E, -MFIX); md[1] = fmaf(rm0.y, LOG2E, -MFIX);
        md[2] = fmaf(rm0.z, LOG2E, -MFIX); md[3] = fmaf(rm0.w, LOG2E, -MFIX);
        md[4] = fmaf(rm1.x, LOG2E, -MFIX); md[5] = fmaf(rm1.y, LOG2E, -MFIX);
        md[6] = fmaf(rm1.z, LOG2E, -MFIX); md[7] = fmaf(rm1.w, LOG2E, -MFIX);
    };

    // prologue
    ld(t0);
    st(0);
    __syncthreads();
    if (t0 + 1 < t1) ld(t0 + 1);

    int cur = 0;
    for (int t = t0; t < t1; ++t) {
        // ---- compute tile t from buf[cur] ----
        f32x4 sc[2][4];
#pragma unroll
        for (int mt = 0; mt < 2; ++mt)
#pragma unroll
            for (int nt = 0; nt < 4; ++nt) sc[mt][nt] = (f32x4){0.f, 0.f, 0.f, 0.f};
#pragma unroll
        for (int nt = 0; nt < 4; ++nt) {
#pragma unroll
            for (int ks = 0; ks < 4; ++ks) {
                bf16x8 bk = *(const bf16x8*)(Ksh[cur] + (nt * 16 + l15) * 136 + ks * 32 + l4 * 8);
                sc[0][nt] = mfma16(aq[0][ks], bk, sc[0][nt]);
                sc[1][nt] = mfma16(aq[1][ks], bk, sc[1][nt]);
            }
        }

        // fixed-max softmax: p = exp2(sc + msh), msh = mask*log2e - MFIX
#pragma unroll
        for (int mt = 0; mt < 2; ++mt) {
#pragma unroll
            for (int r = 0; r < 4; ++r) {
                const int q = qbase + mt * 16 + l4 * 4 + r;
                const float* mq = Msh[cur] + q * 68 + l15;
                sc[mt][0][r] = exp2f(sc[mt][0][r] + mq[0]);
                sc[mt][1][r] = exp2f(sc[mt][1][r] + mq[16]);
                sc[mt][2][r] = exp2f(sc[mt][2][r] + mq[32]);
                sc[mt][3][r] = exp2f(sc[mt][3][r] + mq[48]);
            }
        }

        // O += P V ; l += P 1
#pragma unroll
        for (int ks = 0; ks < 2; ++ks) {
#pragma unroll
            for (int mt = 0; mt < 2; ++mt)
#pragma unroll
                for (int r = 0; r < 4; ++r) {
                    P[(mt * 16 + l4 * 4 + r) * 40 + l15]      = f2bf(sc[mt][ks * 2 + 0][r]);
                    P[(mt * 16 + l4 * 4 + r) * 40 + 16 + l15] = f2bf(sc[mt][ks * 2 + 1][r]);
                }
            bf16x8 ap0 = *(const bf16x8*)(P + (l15) * 40 + l4 * 8);
            bf16x8 ap1 = *(const bf16x8*)(P + (16 + l15) * 40 + l4 * 8);
#pragma unroll
            for (int nt = 0; nt < 8; ++nt) {
                bf16x8 bv = *(const bf16x8*)(Vsh[cur] + (nt * 16 + l15) * 72 + ks * 32 + l4 * 8);
                o[0][nt] = mfma16(ap0, bv, o[0][nt]);
                o[1][nt] = mfma16(ap1, bv, o[1][nt]);
            }
            ol[0] = mfma16(ap0, bones, ol[0]);
            ol[1] = mfma16(ap1, bones, ol[1]);
        }

        // ---- stage tile t+1 into buf[cur^1]; prefetch t+2 ----
        if (t + 1 < t1) st(cur ^ 1);      // waits vmcnt for ld(t+1) regs here
        __syncthreads();                  // vmcnt already 0: no drain cost
        if (t + 2 < t1) ld(t + 2);        // in flight across next compute
        cur ^= 1;
    }

    // coalesced epilogue: Opart chunk per (b,h,s) = [qh][mt][nt][lane][r] u16
    {
        u16* ob = Opart + ((size_t)((b * 16 + h) * S + s)) * 8192;
#pragma unroll
        for (int mt = 0; mt < 2; ++mt)
#pragma unroll
            for (int nt = 0; nt < 8; ++nt) {
                u16x4 v;
#pragma unroll
                for (int r = 0; r < 4; ++r) v[r] = f2bf(o[mt][nt][r]);
                *(u16x4*)(ob + (((qh * 2 + mt) * 8 + nt) * 64 + lane) * 4) = v;
            }
        if (l15 == 0) {
#pragma unroll
            for (int mt = 0; mt < 2; ++mt)
#pragma unroll
                for (int r = 0; r < 4; ++r) {
                    const int q = qbase + mt * 16 + l4 * 4 + r;
                    lsum[((size_t)((b * 16 + h) * 64 + q)) * S + s] = ol[mt][r];
                }
        }
    }
}

// ---------------- merge splits -> attn (B,K,NH*HD) f32 --------------------
template <int S>
__global__ __launch_bounds__(256) void merge_kernel(
    const u16* __restrict__ Opart, const float* __restrict__ lsum, float* __restrict__ attnb)
{
    const int wid = blockIdx.x * 4 + (threadIdx.x >> 6);   // (b*16+h)*2 + qh
    const int lane = threadIdx.x & 63;
    const int l15 = lane & 15, l4 = lane >> 4;
    const int qh = wid & 1, bh = wid >> 1;
    const int h = bh & 15, b = bh >> 4;

    float L = 0.f;
    {
        const float* lr = lsum + ((size_t)bh * 64 + qh * 32 + (lane & 31)) * S;
#pragma unroll
        for (int s2 = 0; s2 < S; ++s2) L += lr[s2];
    }
    const float invL = 1.0f / L;

    float acc[2][8][4];
#pragma unroll
    for (int mt = 0; mt < 2; ++mt)
#pragma unroll
        for (int nt = 0; nt < 8; ++nt)
#pragma unroll
            for (int r = 0; r < 4; ++r) acc[mt][nt][r] = 0.f;

    for (int s2 = 0; s2 < S; ++s2) {
        const u16* ob = Opart + ((size_t)(bh * S + s2)) * 8192;
#pragma unroll
        for (int mt = 0; mt < 2; ++mt)
#pragma unroll
            for (int nt = 0; nt < 8; ++nt) {
                u16x4 v = *(const u16x4*)(ob + (((qh * 2 + mt) * 8 + nt) * 64 + lane) * 4);
#pragma unroll
                for (int r = 0; r < 4; ++r) acc[mt][nt][r] += bf2f(v[r]);
            }
    }

#pragma unroll
    for (int mt = 0; mt < 2; ++mt)
#pragma unroll
        for (int r = 0; r < 4; ++r) {
            const float wl = __shfl(invL, mt * 16 + l4 * 4 + r);
            const int q = qh * 32 + mt * 16 + l4 * 4 + r;
            float* dst = attnb + (size_t)(b * 64 + q) * 2048 + h * 128;
#pragma unroll
            for (int nt = 0; nt < 8; ++nt)
                dst[nt * 16 + l15] = acc[mt][nt][r] * wl;
        }
}

// ---------------- launch ----------------
extern "C" void kernel_launch(void* const* d_in, const int* in_sizes, int n_in,
                              void* d_out, int out_size, void* d_ws, size_t ws_size,
                              hipStream_t stream)
{
    (void)in_sizes; (void)n_in; (void)out_size; (void)ws_size;
    const float* hs   = (const float*)d_in[0];
    const float* ctxk = (const float*)d_in[1];
    const float* ctxv = (const float*)d_in[2];
    const float* mask = (const float*)d_in[3];
    const float* cosT = (const float*)d_in[4];
    const float* sinT = (const float*)d_in[5];
    const float* wq   = (const float*)d_in[6];
    const float* wk   = (const float*)d_in[7];
    const float* wv   = (const float*)d_in[8];
    const float* wo   = (const float*)d_in[9];
    const float* qnw  = (const float*)d_in[10];
    const float* knw  = (const float*)d_in[11];

    const int S = 8;   // grid 256 = 1 block/CU; pipelined dbuf attn

    char* ws = (char*)d_ws;
    size_t off = 0;
    auto carve = [&](size_t bytes) -> void* {
        void* p = ws + off;
        off += (bytes + 255) & ~(size_t)255;
        return p;
    };
    float* qkv   = (float*)carve((size_t)512 * 3072 * 4);
    u16*   Qb    = (u16*)carve((size_t)BB * NH * 64 * 128 * 2);
    u16*   Kb    = (u16*)carve((size_t)BB * NKV * TTOT * 128 * 2);
    u16*   VtG   = (u16*)carve((size_t)BB * NKV * TTOT * 128 * 2);
    u16*   Opart = (u16*)carve((size_t)BB * NH * S * 8192 * 2);
    float* lsumb = (float*)carve((size_t)BB * NH * 64 * S * 4);
    float* attnb = (float*)carve((size_t)512 * 2048 * 4);

    gemm_qkv<<<dim3(8, 48), 256, 0, stream>>>(hs, wq, wk, wv, qkv);
    finalize_q <<<1024,  256, 0, stream>>>(qkv, qnw, cosT, sinT, Qb);
    build_k    <<<16384, 256, 0, stream>>>(ctxk, knw, cosT, sinT, Kb);
    build_vt   <<<dim3(64, NKV, BB), 256, 0, stream>>>(ctxv, VtG);
    build_noise<<<256,   256, 0, stream>>>(qkv, knw, cosT, sinT, Kb, VtG);
    attn_partial<8><<<dim3(8, NKV, BB), 512, 0, stream>>>(Qb, Kb, VtG, mask, Opart, lsumb);
    merge_kernel<8><<<64, 256, 0, stream>>>(Opart, lsumb, attnb);
    gemm64<<<dim3(8, 32), 256, 0, stream>>>(attnb, wo, (float*)d_out, 2048, 2048);
}